// Round 1
// baseline (187.739 us; speedup 1.0000x reference)
//
#include <hip/hip_runtime.h>

// ---------------- fixed problem geometry (validated by out_size) -------------
#define NBATCH   8
#define TT       8
#define NPTS     6890
#define KCLS     7
#define CCH      128
#define BSAMP    64            // NBATCH*TT
#define NOUT     1722          // n = NPTS/4
#define DSUM     512
#define PCADIM   64
#define V3       23106         // 7702*3
#define EPSBN    1e-5f

#define JTILE    64
#define NTILES   ((NOUT + JTILE - 1) / JTILE)   // 27

// output layout (flat f32)
#define OFF_GV     0
#define OFF_GF     (BSAMP * NOUT * 3)                 // 330624
#define OFF_COEFF  (OFF_GF + BSAMP * NOUT * CCH)      // 14437248
#define OFF_TPOSE  (OFF_COEFF + NBATCH * PCADIM)      // 14437760

// ---------------- kernel 1: per-sample stable compaction ---------------------
__global__ __launch_bounds__(256) void k1_compact(
    const float* __restrict__ x,         // [BSAMP, NPTS, 3]
    const float* __restrict__ logits,    // [BSAMP, NPTS, KCLS]
    const int*   __restrict__ d_label,
    float*       __restrict__ gv,        // [BSAMP, NOUT, 3]
    int*         __restrict__ ws_count,  // [BSAMP]
    int*         __restrict__ ws_idx)    // [BSAMP, NOUT]
{
    const int b    = blockIdx.x;
    const int tid  = threadIdx.x;
    const int lane = tid & 63;
    const int wid  = tid >> 6;
    const int label = d_label[0];

    __shared__ int s_cnt;
    __shared__ int wcnt[4];
    if (tid == 0) s_cnt = 0;
    __syncthreads();

    const float* xb = x      + (size_t)b * NPTS * 3;
    const float* lb = logits + (size_t)b * NPTS * KCLS;

    for (int base = 0; base < NPTS; base += 256) {
        const int i = base + tid;
        bool sel = false;
        if (i < NPTS) {
            const float* p = lb + (size_t)i * KCLS;
            float best = p[0]; int bi = 0;
            #pragma unroll
            for (int k = 1; k < KCLS; ++k) {
                float v = p[k];
                if (v > best) { best = v; bi = k; }
            }
            sel = (bi == label);
        }
        const unsigned long long m = __ballot(sel);
        if (lane == 0) wcnt[wid] = __popcll(m);
        __syncthreads();
        int off = s_cnt;
        for (int w = 0; w < wid; ++w) off += wcnt[w];
        const int pos = off + __popcll(m & ((1ull << lane) - 1ull));
        if (sel && pos < NOUT) {
            ws_idx[b * NOUT + pos] = i;
            const size_t go = ((size_t)b * NOUT + pos) * 3;
            gv[go + 0] = xb[(size_t)i * 3 + 0];
            gv[go + 1] = xb[(size_t)i * 3 + 1];
            gv[go + 2] = xb[(size_t)i * 3 + 2];
        }
        __syncthreads();
        if (tid == 0) s_cnt += wcnt[0] + wcnt[1] + wcnt[2] + wcnt[3];
        __syncthreads();
    }

    int cnt = s_cnt;
    if (cnt > NOUT) cnt = NOUT;
    if (tid == 0) ws_count[b] = cnt;

    // zero tail of garment_v (valid mask == 0 region)
    for (int j = cnt + tid; j < NOUT; j += 256) {
        const size_t go = ((size_t)b * NOUT + j) * 3;
        gv[go + 0] = 0.f; gv[go + 1] = 0.f; gv[go + 2] = 0.f;
    }
}

// ---------------- kernel 2: feature gather + transpose -----------------------
__global__ __launch_bounds__(256) void k2_gather(
    const float* __restrict__ feature,   // [BSAMP, CCH, NPTS]
    const int*   __restrict__ ws_count,
    const int*   __restrict__ ws_idx,
    float*       __restrict__ gf)        // [BSAMP, NOUT, CCH]
{
    __shared__ float lds[CCH * 65];      // [c][j], pad 65 -> bank-conflict-free
    __shared__ int   sidx[JTILE];

    const int blk  = blockIdx.x;
    const int b    = blk / NTILES;
    const int tile = blk % NTILES;
    const int j0   = tile * JTILE;
    const int tid  = threadIdx.x;

    const int jcount = min(JTILE, NOUT - j0);       // valid output rows in tile
    const int cnt    = ws_count[b];
    int nsel = cnt - j0;
    if (nsel > jcount) nsel = jcount;

    float* out = gf + ((size_t)b * NOUT + j0) * CCH;

    if (nsel <= 0) {
        const int total = jcount * CCH;
        for (int lin = tid; lin < total; lin += 256) out[lin] = 0.f;
        return;
    }

    if (tid < nsel) sidx[tid] = ws_idx[b * NOUT + j0 + tid];
    __syncthreads();

    const float* fb = feature + (size_t)b * CCH * NPTS;
    const int j  = tid & 63;
    const int c0 = tid >> 6;
    #pragma unroll 4
    for (int it = 0; it < 32; ++it) {
        const int c = it * 4 + c0;
        float v = 0.f;
        if (j < nsel) v = fb[(size_t)c * NPTS + sidx[j]];
        lds[c * 65 + j] = v;
    }
    __syncthreads();

    const int total = jcount * CCH;
    for (int lin = tid; lin < total; lin += 256) {
        const int jj = lin >> 7;
        const int c  = lin & 127;
        out[lin] = lds[c * 65 + jj];
    }
}

// ---------------- kernel 3: max over T + 3-layer MLP (BN eval) ---------------
__global__ __launch_bounds__(256) void k3_mlp(
    const float* __restrict__ gsum,      // [NBATCH, TT, DSUM]
    const float* __restrict__ W1, const float* __restrict__ b1,
    const float* __restrict__ g1, const float* __restrict__ be1,
    const float* __restrict__ rm1, const float* __restrict__ rv1,
    const float* __restrict__ W2, const float* __restrict__ b2,
    const float* __restrict__ g2, const float* __restrict__ be2,
    const float* __restrict__ rm2, const float* __restrict__ rv2,
    const float* __restrict__ W3, const float* __restrict__ b3,
    float* __restrict__ coeff_out,       // d_out + OFF_COEFF
    float* __restrict__ coeff_ws)        // workspace copy for k4
{
    __shared__ float gs[NBATCH * DSUM];  // 16 KB
    __shared__ float h1[NBATCH * 128];
    __shared__ float h2[NBATCH * 64];
    const int tid = threadIdx.x;

    for (int o = tid; o < NBATCH * DSUM; o += 256) {
        const int s = o / DSUM, d = o % DSUM;
        const float* p = gsum + ((size_t)s * TT) * DSUM + d;
        float m = p[0];
        #pragma unroll
        for (int t = 1; t < TT; ++t) m = fmaxf(m, p[(size_t)t * DSUM]);
        gs[o] = m;
    }
    __syncthreads();

    for (int o = tid; o < NBATCH * 128; o += 256) {
        const int s = o >> 7, jj = o & 127;
        const float* w  = W1 + (size_t)jj * DSUM;
        const float* gp = gs + s * DSUM;
        float acc = 0.f;
        for (int d = 0; d < DSUM; ++d) acc = fmaf(w[d], gp[d], acc);
        acc += b1[jj];
        acc = (acc - rm1[jj]) * rsqrtf(rv1[jj] + EPSBN) * g1[jj] + be1[jj];
        h1[o] = fmaxf(acc, 0.f);
    }
    __syncthreads();

    for (int o = tid; o < NBATCH * 64; o += 256) {
        const int s = o >> 6, jj = o & 63;
        const float* w  = W2 + (size_t)jj * 128;
        const float* hp = h1 + s * 128;
        float acc = 0.f;
        #pragma unroll
        for (int d = 0; d < 128; ++d) acc = fmaf(w[d], hp[d], acc);
        acc += b2[jj];
        acc = (acc - rm2[jj]) * rsqrtf(rv2[jj] + EPSBN) * g2[jj] + be2[jj];
        h2[o] = fmaxf(acc, 0.f);
    }
    __syncthreads();

    for (int o = tid; o < NBATCH * 64; o += 256) {
        const int s = o >> 6, jj = o & 63;
        const float* w  = W3 + (size_t)jj * 64;
        const float* hp = h2 + s * 64;
        float acc = 0.f;
        #pragma unroll
        for (int d = 0; d < 64; ++d) acc = fmaf(w[d], hp[d], acc);
        acc += b3[jj];
        coeff_out[o] = acc;
        coeff_ws[o]  = acc;
    }
}

// ---------------- kernel 4: PCA inverse transform ----------------------------
__global__ __launch_bounds__(256) void k4_tpose(
    const float* __restrict__ coeff_ws,  // [NBATCH, PCADIM]
    const float* __restrict__ comp,      // [PCADIM, V3]
    const float* __restrict__ mean_,     // [V3]
    const float* __restrict__ scale_,    // [V3]
    float* __restrict__ tpose)           // [NBATCH, V3]
{
    __shared__ float sc[NBATCH * PCADIM];
    const int tid = threadIdx.x;
    for (int o = tid; o < NBATCH * PCADIM; o += 256) sc[o] = coeff_ws[o];
    __syncthreads();

    const int v = blockIdx.x * 256 + tid;
    if (v >= V3) return;

    float acc[NBATCH];
    #pragma unroll
    for (int s = 0; s < NBATCH; ++s) acc[s] = 0.f;

    for (int k = 0; k < PCADIM; ++k) {
        const float pv = comp[(size_t)k * V3 + v];
        #pragma unroll
        for (int s = 0; s < NBATCH; ++s)
            acc[s] = fmaf(sc[s * PCADIM + k], pv, acc[s]);
    }
    const float mn = mean_[v], scl = scale_[v];
    #pragma unroll
    for (int s = 0; s < NBATCH; ++s)
        tpose[(size_t)s * V3 + v] = (acc[s] + mn) * scl;
}

// ---------------- launcher ---------------------------------------------------
extern "C" void kernel_launch(void* const* d_in, const int* in_sizes, int n_in,
                              void* d_out, int out_size, void* d_ws, size_t ws_size,
                              hipStream_t stream) {
    const float* x      = (const float*)d_in[0];
    const float* logits = (const float*)d_in[1];
    const float* feat   = (const float*)d_in[2];
    const float* gsum   = (const float*)d_in[3];
    const float* W1  = (const float*)d_in[4];
    const float* b1  = (const float*)d_in[5];
    const float* g1  = (const float*)d_in[6];
    const float* be1 = (const float*)d_in[7];
    const float* rm1 = (const float*)d_in[8];
    const float* rv1 = (const float*)d_in[9];
    const float* W2  = (const float*)d_in[10];
    const float* b2  = (const float*)d_in[11];
    const float* g2  = (const float*)d_in[12];
    const float* be2 = (const float*)d_in[13];
    const float* rm2 = (const float*)d_in[14];
    const float* rv2 = (const float*)d_in[15];
    const float* W3  = (const float*)d_in[16];
    const float* b3  = (const float*)d_in[17];
    const float* comp  = (const float*)d_in[18];
    const float* mean_ = (const float*)d_in[19];
    const float* scale_= (const float*)d_in[20];
    const int* d_label = (const int*)d_in[21];
    // d_in[22] is n; layout is compile-time fixed (out_size matches NOUT=1722)

    float* out   = (float*)d_out;
    float* gv    = out + OFF_GV;
    float* gf    = out + OFF_GF;
    float* coeff = out + OFF_COEFF;
    float* tpose = out + OFF_TPOSE;

    int*   ws_count = (int*)d_ws;
    int*   ws_idx   = ws_count + 64;
    float* coeff_ws = (float*)(ws_idx + BSAMP * NOUT);

    k1_compact<<<BSAMP, 256, 0, stream>>>(x, logits, d_label, gv, ws_count, ws_idx);
    k2_gather<<<BSAMP * NTILES, 256, 0, stream>>>(feat, ws_count, ws_idx, gf);
    k3_mlp<<<1, 256, 0, stream>>>(gsum, W1, b1, g1, be1, rm1, rv1,
                                  W2, b2, g2, be2, rm2, rv2, W3, b3,
                                  coeff, coeff_ws);
    k4_tpose<<<(V3 + 255) / 256, 256, 0, stream>>>(coeff_ws, comp, mean_, scale_, tpose);
}